// Round 4
// baseline (458.711 us; speedup 1.0000x reference)
//
#include <hip/hip_runtime.h>

// VectorQuantizer on MI355X — bit-exact replication of the numpy fp32 reference.
//
// The np ref computes, in float32:
//   xx[n] = np.sum(flat*flat, 1)   (pairwise sum, products pre-rounded)
//   ee[k] = np.sum(emb*emb, 1)     (pairwise sum)
//   d[n,k] = fl( fl(xx[n] + ee[k]) - 2*dot_blas(n,k) ),  argmin first-min.
// BLAS sgemm accumulates dot k-sequentially with a single fp32 FMA accumulator,
// which our ascending-d fmaf chain replicates bit-exactly. The +xx term puts
// distances on a ~1.5e-5 grid -> many exact ties -> lowest-index tie-break
// everywhere. No fp64 anywhere (fp64-true argmin DIFFERS from the ref: R2/R3
// both failed with identical absmax 789 = a quantized tie pair).
//
// X: inputs [B=32, D=256, H=32, W=32] fp32; row n = b*1024 + h*32 + w;
//    x[n][d] = in[b*262144 + d*1024 + (n&1023)].
// E: embeddings [K=1024, D=256] fp32 row-major.
// Outputs (float32): [0,8388608) quantized_st, [8388608] loss,
// [8388609] perplexity, [8388610,8421378) indices (as float).
//
// ws (float units): W+0 sumsq | W+64 counts[1024] | W+1088 ee[1024]
//   | W+2112 xx[32768] | W+34880 partv[4*32768] | W+165952 parti[4*32768]
//   | W+297024 fidx[32768]  -> ~1.26 MB total.

#define NROWS 32768

// numpy pairwise sum of squares over 256 elements: pw128 + pw128.
// pw128: r[j]=v[j]; 15x r[j]+=v[8i+j]; ((r0+r1)+(r2+r3))+((r4+r5)+(r6+r7)).
// Products rounded separately (__fmul_rn) exactly like the materialized a*a.
template <int STRIDE>
__device__ __forceinline__ float np_sumsq256(const float* __restrict__ p) {
    float half[2];
#pragma unroll
    for (int h = 0; h < 2; ++h) {
        float r[8];
#pragma unroll
        for (int j = 0; j < 8; ++j) {
            const float v = p[(size_t)(h * 128 + j) * STRIDE];
            r[j] = __fmul_rn(v, v);
        }
        for (int i = 8; i < 128; i += 8) {
#pragma unroll
            for (int j = 0; j < 8; ++j) {
                const float v = p[(size_t)(h * 128 + i + j) * STRIDE];
                r[j] = __fadd_rn(r[j], __fmul_rn(v, v));
            }
        }
        half[h] = __fadd_rn(__fadd_rn(__fadd_rn(r[0], r[1]), __fadd_rn(r[2], r[3])),
                            __fadd_rn(__fadd_rn(r[4], r[5]), __fadd_rn(r[6], r[7])));
    }
    return __fadd_rn(half[0], half[1]);
}

__global__ void ee_kernel(const float* __restrict__ emb, float* __restrict__ ee) {
    const int k = blockIdx.x * blockDim.x + threadIdx.x;
    if (k >= 1024) return;
    ee[k] = np_sumsq256<1>(emb + (size_t)k * 256);
}

__global__ void xx_kernel(const float* __restrict__ x, float* __restrict__ xx) {
    const int n = blockIdx.x * blockDim.x + threadIdx.x;
    if (n >= NROWS) return;
    const int b = n >> 10, p = n & 1023;
    xx[n] = np_sumsq256<1024>(x + (size_t)b * 262144 + p);
}

// Tiled score-GEMM + per-row running argmin over np-fp32 distances.
// Grid: 1024 blocks = 256 row-tiles (128 rows) x 4 K-splits (256 codes each).
// Each thread: 8x8 register tile; dot accumulated d=0..255 sequential fmaf
// (bit-exact to sgemm); distance fold replicates fl(fl(xx+ee)-2*dot).
__global__ __launch_bounds__(256)
void argmin_kernel(const float* __restrict__ x, const float* __restrict__ emb,
                   const float* __restrict__ ee, const float* __restrict__ xx,
                   float* __restrict__ partv, int* __restrict__ parti) {
    __shared__ float Xs[32][132];
    __shared__ float Es[32][132];
    const int t  = threadIdx.x;
    const int tx = t & 15, ty = t >> 4;
    const int rowblk = blockIdx.x >> 2;
    const int ksplit = blockIdx.x & 3;
    const int row0 = rowblk * 128;
    const int b  = row0 >> 10;          // 128 | 1024 so one image per row-tile
    const int p0 = row0 & 1023;
    const float* xb = x + (size_t)b * 262144 + p0;   // index with d*1024 + r

    float xxr[8];
#pragma unroll
    for (int i = 0; i < 8; ++i) {
        const int r = (i < 4) ? (ty * 4 + i) : (64 + ty * 4 + (i - 4));
        xxr[i] = xx[row0 + r];
    }

    float best[8];
    int   bidx[8];
#pragma unroll
    for (int i = 0; i < 8; ++i) { best[i] = 3.4e38f; bidx[i] = 0x7fffffff; }

    for (int kt = 0; kt < 2; ++kt) {
        const int k0 = ksplit * 256 + kt * 128;
        float acc[8][8];
#pragma unroll
        for (int i = 0; i < 8; ++i)
#pragma unroll
            for (int j = 0; j < 8; ++j) acc[i][j] = 0.f;

        for (int dc = 0; dc < 8; ++dc) {
            const int d0 = dc * 32;
            __syncthreads();   // protect LDS from previous iteration's readers
            {   // X tile: lanes -> consecutive r (coalesced 512B rows)
                const int r4  = (t & 31) * 4;
                const int ddb = t >> 5;
#pragma unroll
                for (int i = 0; i < 4; ++i) {
                    const int dd = ddb + i * 8;
                    float4 v = *(const float4*)(xb + (size_t)(d0 + dd) * 1024 + r4);
                    *(float4*)&Xs[dd][r4] = v;
                }
            }
            {   // E tile: float4 along d, transpose into LDS
                const int c0  = t >> 3;
                const int dd4 = (t & 7) * 4;
#pragma unroll
                for (int i = 0; i < 4; ++i) {
                    const int c = c0 + i * 32;
                    float4 v = *(const float4*)(emb + (size_t)(k0 + c) * 256 + d0 + dd4);
                    Es[dd4 + 0][c] = v.x; Es[dd4 + 1][c] = v.y;
                    Es[dd4 + 2][c] = v.z; Es[dd4 + 3][c] = v.w;
                }
            }
            __syncthreads();
#pragma unroll
            for (int dd = 0; dd < 32; ++dd) {   // ascending d: sgemm-exact chain
                float a0[8], b0[8];
                float4 va = *(const float4*)&Xs[dd][ty * 4];
                float4 vb = *(const float4*)&Xs[dd][64 + ty * 4];
                float4 vc = *(const float4*)&Es[dd][tx * 4];
                float4 vd = *(const float4*)&Es[dd][64 + tx * 4];
                a0[0]=va.x; a0[1]=va.y; a0[2]=va.z; a0[3]=va.w;
                a0[4]=vb.x; a0[5]=vb.y; a0[6]=vb.z; a0[7]=vb.w;
                b0[0]=vc.x; b0[1]=vc.y; b0[2]=vc.z; b0[3]=vc.w;
                b0[4]=vd.x; b0[5]=vd.y; b0[6]=vd.z; b0[7]=vd.w;
#pragma unroll
                for (int i = 0; i < 8; ++i)
#pragma unroll
                    for (int j = 0; j < 8; ++j)
                        acc[i][j] = __fmaf_rn(a0[i], b0[j], acc[i][j]);
            }
        }
        // Fold: s = fl( fl(xx+ee) - 2*dot ).  2*acc is exact (pow2), so the
        // fmaf equals numpy's two-step rounding. k ascending in-thread; strict
        // '<' keeps lowest k on exact quantized ties (np.argmin first-min).
#pragma unroll
        for (int j = 0; j < 8; ++j) {
            const int c  = (j < 4) ? (tx * 4 + j) : (64 + tx * 4 + (j - 4));
            const int kk = k0 + c;
            const float eek = ee[kk];
#pragma unroll
            for (int i = 0; i < 8; ++i) {
                const float t1 = __fadd_rn(xxr[i], eek);
                const float s  = __fmaf_rn(-2.0f, acc[i][j], t1);
                if (s < best[i]) { best[i] = s; bidx[i] = kk; }
            }
        }
    }
    // Reduce across the 16 tx-lanes of each row group (lowest-k tie-break).
#pragma unroll
    for (int i = 0; i < 8; ++i) {
        float bv = best[i]; int bi = bidx[i];
#pragma unroll
        for (int off = 8; off > 0; off >>= 1) {
            float ov = __shfl_xor(bv, off, 16);
            int   oi = __shfl_xor(bi, off, 16);
            if (ov < bv || (ov == bv && oi < bi)) { bv = ov; bi = oi; }
        }
        if (tx == 0) {
            const int r = (i < 4) ? (ty * 4 + i) : (64 + ty * 4 + (i - 4));
            partv[(size_t)ksplit * NROWS + row0 + r] = bv;
            parti[(size_t)ksplit * NROWS + row0 + r] = bi;
        }
    }
}

// Merge 4 split-K winners (lowest-k ties), write index + histogram.
__global__ void combine_kernel(const float* __restrict__ partv, const int* __restrict__ parti,
                               int* __restrict__ fidx, int* __restrict__ counts,
                               float* __restrict__ outIdx) {
    int n = blockIdx.x * blockDim.x + threadIdx.x;
    if (n >= NROWS) return;
    float bv = 3.4e38f; int bi = 0x7fffffff;
#pragma unroll
    for (int s = 0; s < 4; ++s) {
        float v = partv[s * NROWS + n];
        int   i = parti[s * NROWS + n];
        if (v < bv || (v == bv && i < bi)) { bv = v; bi = i; }
    }
    fidx[n] = bi;
    outIdx[n] = (float)bi;
    atomicAdd(&counts[bi], 1);
}

// Gather + straight-through write + sum((q-x)^2).
__global__ __launch_bounds__(256)
void quantize_kernel(const float* __restrict__ x, const float* __restrict__ emb,
                     const int* __restrict__ fidx, float* __restrict__ out,
                     float* __restrict__ sumsq) {
    const int g4 = blockIdx.x * blockDim.x + threadIdx.x;
    const int g  = g4 * 4;
    const int b  = g >> 18;
    const int d  = (g >> 10) & 255;
    const int p  = g & 1023;
    const int n  = (b << 10) | p;
    float4 xv = *(const float4*)(x + g);
    const int k0 = fidx[n], k1 = fidx[n + 1], k2 = fidx[n + 2], k3 = fidx[n + 3];
    const float q0 = emb[(size_t)k0 * 256 + d];
    const float q1 = emb[(size_t)k1 * 256 + d];
    const float q2 = emb[(size_t)k2 * 256 + d];
    const float q3 = emb[(size_t)k3 * 256 + d];
    const float e0 = q0 - xv.x, e1 = q1 - xv.y, e2 = q2 - xv.z, e3 = q3 - xv.w;
    float4 o;                      // straight-through: x + (q - x)
    o.x = xv.x + e0; o.y = xv.y + e1; o.z = xv.z + e2; o.w = xv.w + e3;
    *(float4*)(out + g) = o;
    float loc = e0 * e0 + e1 * e1 + e2 * e2 + e3 * e3;
    for (int off = 32; off > 0; off >>= 1) loc += __shfl_down(loc, off, 64);
    __shared__ float red[4];
    const int lane = threadIdx.x & 63, wv = threadIdx.x >> 6;
    if (lane == 0) red[wv] = loc;
    __syncthreads();
    if (threadIdx.x == 0) atomicAdd(sumsq, red[0] + red[1] + red[2] + red[3]);
}

// outScalars points at d_out + 8388608: [0]=loss, [1]=perplexity.
__global__ void finalize_kernel(const int* __restrict__ counts, const float* __restrict__ sumsq,
                                float* __restrict__ outScalars) {
    const int k = threadIdx.x;   // 1024 threads
    const float p = (float)counts[k] * (1.0f / 32768.0f);
    float term = p * logf(p + 1e-10f);
    for (int off = 32; off > 0; off >>= 1) term += __shfl_down(term, off, 64);
    __shared__ float red[16];
    const int lane = k & 63, wv = k >> 6;
    if (lane == 0) red[wv] = term;
    __syncthreads();
    if (k == 0) {
        float s = 0.f;
        for (int i = 0; i < 16; ++i) s += red[i];
        const float m = sumsq[0] * (1.0f / 8388608.0f);   // mean((q-x)^2)
        outScalars[0] = 1.25f * m;     // q_latent + 0.25*e_latent
        outScalars[1] = expf(-s);      // perplexity
    }
}

extern "C" void kernel_launch(void* const* d_in, const int* in_sizes, int n_in,
                              void* d_out, int out_size, void* d_ws, size_t ws_size,
                              hipStream_t stream) {
    const float* x   = (const float*)d_in[0];
    const float* emb = (const float*)d_in[1];
    float* out = (float*)d_out;
    float* W   = (float*)d_ws;
    float* sumsq  = W;
    int*   counts = (int*)(W + 64);
    float* ee     = W + 1088;
    float* xx     = W + 2112;
    float* partv  = W + 34880;
    int*   parti  = (int*)(W + 165952);
    int*   fidx   = (int*)(W + 297024);

    hipMemsetAsync(W, 0, 1088 * sizeof(float), stream);  // sumsq + counts
    ee_kernel<<<4, 256, 0, stream>>>(emb, ee);
    xx_kernel<<<128, 256, 0, stream>>>(x, xx);
    argmin_kernel<<<1024, 256, 0, stream>>>(x, emb, ee, xx, partv, parti);
    combine_kernel<<<128, 256, 0, stream>>>(partv, parti, fidx, counts, out + 8388610);
    quantize_kernel<<<8192, 256, 0, stream>>>(x, emb, fidx, out, sumsq);
    finalize_kernel<<<1, 1024, 0, stream>>>(counts, sumsq, out + 8388608);
}